// Round 4
// baseline (728.551 us; speedup 1.0000x reference)
//
#include <hip/hip_runtime.h>

#define N_NODES 100000
#define N_EDGES 1600000
#define D 32
#define ED 8
#define NEG_SLOPE 0.01f
#define NBLK ((N_NODES + 1023) / 1024)  // 98 scan blocks

// ---------------- CSR build ----------------

__global__ __launch_bounds__(256) void hist_kernel(
    const int* __restrict__ dst, int* __restrict__ deg)
{
    int e = blockIdx.x * 256 + threadIdx.x;
    if (e < N_EDGES) atomicAdd(&deg[dst[e]], 1);
}

__global__ __launch_bounds__(1024) void scan_phase1(
    const int* __restrict__ deg, int* __restrict__ bsums)
{
    __shared__ int s[1024];
    int t = threadIdx.x;
    int i = blockIdx.x * 1024 + t;
    s[t] = (i < N_NODES) ? deg[i] : 0;
    __syncthreads();
    for (int off = 512; off > 0; off >>= 1) {
        if (t < off) s[t] += s[t + off];
        __syncthreads();
    }
    if (t == 0) bsums[blockIdx.x] = s[0];
}

__global__ __launch_bounds__(128) void scan_phase2(int* __restrict__ bsums)
{
    __shared__ int s[128];
    int t = threadIdx.x;
    int v = (t < NBLK) ? bsums[t] : 0;
    s[t] = v;
    __syncthreads();
    for (int off = 1; off < 128; off <<= 1) {
        int u = (t >= off) ? s[t - off] : 0;
        __syncthreads();
        s[t] += u;
        __syncthreads();
    }
    if (t < NBLK) bsums[t] = s[t] - v;  // exclusive
}

__global__ __launch_bounds__(1024) void scan_phase3(
    const int* __restrict__ deg, const int* __restrict__ bsums,
    int* __restrict__ row_ptr, int* __restrict__ offs)
{
    __shared__ int s[1024];
    int t = threadIdx.x;
    int i = blockIdx.x * 1024 + t;
    int v = (i < N_NODES) ? deg[i] : 0;
    s[t] = v;
    __syncthreads();
    for (int off = 1; off < 1024; off <<= 1) {
        int u = (t >= off) ? s[t - off] : 0;
        __syncthreads();
        s[t] += u;
        __syncthreads();
    }
    int excl = bsums[blockIdx.x] + s[t] - v;
    if (i < N_NODES) { row_ptr[i] = excl; offs[i] = excl; }
    else if (i == N_NODES) row_ptr[i] = excl;  // == N_EDGES
}

// perm-only scatter: 4B random writes into a 6.4MB region (L2-merged)
__global__ __launch_bounds__(256) void scatter_perm_kernel(
    const int* __restrict__ dst, int* __restrict__ offs, int* __restrict__ perm)
{
    int e = blockIdx.x * 256 + threadIdx.x;
    if (e >= N_EDGES) return;
    int pos = atomicAdd(&offs[dst[e]], 1);
    perm[pos] = e;
}

// gather-permute: coalesced writes, random (L3-resident) reads
__global__ __launch_bounds__(256) void permute_gather_kernel(
    const int*   __restrict__ perm,
    const int*   __restrict__ src,
    const float* __restrict__ edge_attr,
    int*         __restrict__ src_sorted,
    float*       __restrict__ ea_sorted)
{
    int i = blockIdx.x * 256 + threadIdx.x;
    if (i >= N_EDGES) return;
    int p = perm[i];
    src_sorted[i] = src[p];
    const float4* ea4 = (const float4*)edge_attr;
    float4* es4 = (float4*)ea_sorted;
    es4[(long)i * 2]     = ea4[(long)p * 2];
    es4[(long)i * 2 + 1] = ea4[(long)p * 2 + 1];
}

// ---------------- fused GINE layer (batch-8 edge loop) ----------------
__global__ __launch_bounds__(256) void gine_fused_kernel(
    const float* __restrict__ x_in,
    float*       __restrict__ x_out,
    const int*   __restrict__ row_ptr,
    const int*   __restrict__ src_sorted,
    const float* __restrict__ ea_sorted,
    const float* __restrict__ W,    // [32][32]
    const float* __restrict__ b,    // [32]
    const float* __restrict__ We,   // [8][32]
    const float* __restrict__ be)   // [32]
{
    __shared__ float W_s[D * D];
    __shared__ float We_s[ED * D];
    __shared__ float b_s[D];
    __shared__ float be_s[D];
    const int t = threadIdx.x;
    for (int i = t; i < D * D; i += 256) W_s[i] = W[i];
    if (t < ED * D) We_s[t] = We[t];
    if (t < D) { b_s[t] = b[t]; be_s[t] = be[t]; }
    __syncthreads();

    const int n = blockIdx.x * 8 + (t >> 5);
    const int d = t & 31;
    if (n >= N_NODES) return;

    const int row  = row_ptr[n];
    const int rend = row_ptr[n + 1];

    float selfx = x_in[(long)n * D + d];  // issue early, consumed after loop

    float acc = 0.0f;
    for (int pos = row; pos < rend; pos += 8) {
        const int rem = rend - pos;  // >= 1
        // 4 edges' ea per coalesced 128B load, shfl'd out below
        float eav0 = ea_sorted[(long)pos * ED + d];
        float eav1 = (rem > 4) ? ea_sorted[(long)(pos + 4) * ED + d] : 0.0f;
        int4 sA = *(const int4*)(src_sorted + pos);          // broadcast 16B
        int4 sB = (rem > 4) ? *(const int4*)(src_sorted + pos + 4) : sA;
        int ss[8] = { sA.x, sA.y, sA.z, sA.w, sB.x, sB.y, sB.z, sB.w };
        const int s0 = sA.x;  // always valid (rem >= 1)

        // phase 1: issue up to 8 independent gathers (clamped-safe addresses)
        float xv[8];
#pragma unroll
        for (int j = 0; j < 8; ++j) {
            int sj = (j < rem) ? ss[j] : s0;
            xv[j] = x_in[(long)sj * D + d];
        }
        // phase 2: branch-free compute, predicated accumulate
#pragma unroll
        for (int j = 0; j < 8; ++j) {
            float eav = (j < 4) ? eav0 : eav1;
            float e = be_s[d];
#pragma unroll
            for (int k = 0; k < ED; ++k)
                e += __shfl(eav, (j & 3) * ED + k, 32) * We_s[k * D + d];
            float m = fmaxf(xv[j] + e, 0.0f);
            acc += (j < rem) ? m : 0.0f;
        }
    }

    float h = selfx + acc;
    float o = b_s[d];
#pragma unroll
    for (int k = 0; k < D; ++k)
        o += __shfl(h, k, 32) * W_s[k * D + d];
    o = o > 0.0f ? o : NEG_SLOPE * o;
    x_out[(long)n * D + d] = o;
}

// ---------------- round-1 fallback (atomics) ----------------
__global__ __launch_bounds__(256) void gine_edge_kernel(
    const float* __restrict__ x, const float* __restrict__ edge_attr,
    const float* __restrict__ We, const float* __restrict__ be,
    const int* __restrict__ src, const int* __restrict__ dst,
    float* __restrict__ agg)
{
    __shared__ float We_s[ED * D];
    __shared__ float be_s[D];
    int t = threadIdx.x;
    if (t < ED * D) We_s[t] = We[t];
    if (t < D) be_s[t] = be[t];
    __syncthreads();
    long gtid = (long)blockIdx.x * blockDim.x + t;
    int e = (int)(gtid >> 5), d = (int)(gtid & 31);
    if (e >= N_EDGES) return;
    int s = src[e], dn = dst[e];
    float acc = be_s[d];
#pragma unroll
    for (int k = 0; k < ED; ++k)
        acc += edge_attr[(long)e * ED + k] * We_s[k * D + d];
    float m = fmaxf(x[(long)s * D + d] + acc, 0.0f);
    atomicAdd(&agg[(long)dn * D + d], m);
}

__global__ __launch_bounds__(256) void gine_node_kernel(
    float* __restrict__ x, const float* __restrict__ agg,
    const float* __restrict__ W, const float* __restrict__ b)
{
    __shared__ float W_s[D * D];
    __shared__ float b_s[D];
    int t = threadIdx.x;
    for (int i = t; i < D * D; i += 256) W_s[i] = W[i];
    if (t < D) b_s[t] = b[t];
    __syncthreads();
    long gtid = (long)blockIdx.x * blockDim.x + t;
    int n = (int)(gtid >> 5), d = (int)(gtid & 31);
    if (n >= N_NODES) return;
    float h = x[(long)n * D + d] + agg[(long)n * D + d];
    float acc = b_s[d];
#pragma unroll
    for (int k = 0; k < D; ++k)
        acc += __shfl(h, k, D) * W_s[k * D + d];
    x[(long)n * D + d] = acc > 0.0f ? acc : NEG_SLOPE * acc;
}

// ---------------- launch ----------------

extern "C" void kernel_launch(void* const* d_in, const int* in_sizes, int n_in,
                              void* d_out, int out_size, void* d_ws, size_t ws_size,
                              hipStream_t stream) {
    const float* x_in      = (const float*)d_in[0];
    const float* edge_attr = (const float*)d_in[1];
    const float* W         = (const float*)d_in[2];
    const float* b         = (const float*)d_in[3];
    const float* We        = (const float*)d_in[4];
    const float* be        = (const float*)d_in[5];
    const int*   ei        = (const int*)d_in[6];
    const int* src = ei;
    const int* dst = ei + N_EDGES;

    const size_t xbytes = (size_t)N_NODES * D * sizeof(float);

    // ws layout — bsums placed LAST so the fused kernel's batched tail
    // over-reads of src_sorted (+28B) / ea_sorted (+224B) land in allocated
    // space. Total `need` identical to round 2 (which fit).
    auto align = [](size_t v) { return (v + 255) & ~(size_t)255; };
    size_t off_wsx  = 0;
    size_t off_rp   = align(off_wsx + xbytes);                         // row_ptr (N+1)
    size_t off_offs = align(off_rp + (N_NODES + 1) * sizeof(int));     // offs (N)
    size_t off_deg  = align(off_offs + N_NODES * sizeof(int));         // deg (N)
    size_t off_srcs = align(off_deg + N_NODES * sizeof(int));          // src_sorted (E)
    size_t off_eas  = align(off_srcs + (size_t)N_EDGES * sizeof(int)); // ea_sorted (E*8)
    size_t off_bs   = align(off_eas + (size_t)N_EDGES * ED * sizeof(float)); // bsums(128) — sacrificial pad
    size_t need     = off_bs + 128 * sizeof(int);

    if (ws_size >= need) {
        char* ws = (char*)d_ws;
        float* ws_x       = (float*)(ws + off_wsx);
        int*   perm       = (int*)  (ws + off_wsx);  // aliases ws_x: dead until layer 1 writes it
        int*   row_ptr    = (int*)  (ws + off_rp);
        int*   offs       = (int*)  (ws + off_offs);
        int*   deg        = (int*)  (ws + off_deg);
        int*   src_sorted = (int*)  (ws + off_srcs);
        float* ea_sorted  = (float*)(ws + off_eas);
        int*   bsums      = (int*)  (ws + off_bs);

        hipMemsetAsync(deg, 0, N_NODES * sizeof(int), stream);
        hist_kernel<<<(N_EDGES + 255) / 256, 256, 0, stream>>>(dst, deg);
        scan_phase1<<<NBLK, 1024, 0, stream>>>(deg, bsums);
        scan_phase2<<<1, 128, 0, stream>>>(bsums);
        scan_phase3<<<NBLK, 1024, 0, stream>>>(deg, bsums, row_ptr, offs);
        scatter_perm_kernel<<<(N_EDGES + 255) / 256, 256, 0, stream>>>(dst, offs, perm);
        permute_gather_kernel<<<(N_EDGES + 255) / 256, 256, 0, stream>>>(
            perm, src, edge_attr, src_sorted, ea_sorted);

        float* xout = (float*)d_out;
        dim3 blk(256), grid((N_NODES + 7) / 8);
        gine_fused_kernel<<<grid, blk, 0, stream>>>(x_in, xout, row_ptr, src_sorted,
            ea_sorted, W, b, We, be);
        gine_fused_kernel<<<grid, blk, 0, stream>>>(xout, ws_x, row_ptr, src_sorted,
            ea_sorted, W + D * D, b + D, We + ED * D, be + D);
        gine_fused_kernel<<<grid, blk, 0, stream>>>(ws_x, xout, row_ptr, src_sorted,
            ea_sorted, W + 2 * D * D, b + 2 * D, We + 2 * ED * D, be + 2 * D);
    } else {
        float* x = (float*)d_out;
        float* agg = (float*)d_ws;
        hipMemcpyAsync(x, x_in, xbytes, hipMemcpyDeviceToDevice, stream);
        dim3 eblk(256), egrid(((long)N_EDGES * D + 255) / 256);
        dim3 nblk(256), ngrid(((long)N_NODES * D + 255) / 256);
        for (int l = 0; l < 3; ++l) {
            hipMemsetAsync(agg, 0, xbytes, stream);
            gine_edge_kernel<<<egrid, eblk, 0, stream>>>(
                x, edge_attr, We + (size_t)l * ED * D, be + (size_t)l * D, src, dst, agg);
            gine_node_kernel<<<ngrid, nblk, 0, stream>>>(
                x, agg, W + (size_t)l * D * D, b + (size_t)l * D);
        }
    }
}

// Round 5
// 529.646 us; speedup vs baseline: 1.3755x; 1.3755x over previous
//
#include <hip/hip_runtime.h>

#define N_NODES 100000
#define N_EDGES 1600000
#define D 32
#define ED 8
#define NEG_SLOPE 0.01f
#define NBLK ((N_NODES + 1023) / 1024)  // 98 scan blocks

typedef unsigned int uint;
typedef unsigned short ushort;

__device__ __forceinline__ uint bf16_rne(float f) {
    uint u = __float_as_uint(f);
    return (u + 0x7fffu + ((u >> 16) & 1u)) >> 16;
}
__device__ __forceinline__ uint pack2(float lo, float hi) {
    return bf16_rne(lo) | (bf16_rne(hi) << 16);
}
__device__ __forceinline__ float bf_lo(uint u) { return __uint_as_float(u << 16); }
__device__ __forceinline__ float bf_hi(uint u) { return __uint_as_float(u & 0xffff0000u); }
__device__ __forceinline__ float bf_us(ushort u) { return __uint_as_float(((uint)u) << 16); }

// ---------------- x -> bf16 pack ----------------
__global__ __launch_bounds__(256) void pack_x_kernel(
    const float* __restrict__ x, ushort* __restrict__ xb)
{
    int i = blockIdx.x * 256 + threadIdx.x;     // over N*D/4
    if (i >= N_NODES * D / 4) return;
    float4 f = ((const float4*)x)[i];
    ((uint2*)xb)[i] = make_uint2(pack2(f.x, f.y), pack2(f.z, f.w));
}

// ---------------- CSR build ----------------
__global__ __launch_bounds__(256) void hist_kernel(
    const int* __restrict__ dst, int* __restrict__ deg)
{
    int i = blockIdx.x * 256 + threadIdx.x;     // over E/4
    if (i >= N_EDGES / 4) return;
    int4 dd = ((const int4*)dst)[i];
    atomicAdd(&deg[dd.x], 1);
    atomicAdd(&deg[dd.y], 1);
    atomicAdd(&deg[dd.z], 1);
    atomicAdd(&deg[dd.w], 1);
}

__global__ __launch_bounds__(1024) void scan_phase1(
    const int* __restrict__ deg, int* __restrict__ bsums)
{
    __shared__ int s[1024];
    int t = threadIdx.x;
    int i = blockIdx.x * 1024 + t;
    s[t] = (i < N_NODES) ? deg[i] : 0;
    __syncthreads();
    for (int off = 512; off > 0; off >>= 1) {
        if (t < off) s[t] += s[t + off];
        __syncthreads();
    }
    if (t == 0) bsums[blockIdx.x] = s[0];
}

__global__ __launch_bounds__(128) void scan_phase2(int* __restrict__ bsums)
{
    __shared__ int s[128];
    int t = threadIdx.x;
    int v = (t < NBLK) ? bsums[t] : 0;
    s[t] = v;
    __syncthreads();
    for (int off = 1; off < 128; off <<= 1) {
        int u = (t >= off) ? s[t - off] : 0;
        __syncthreads();
        s[t] += u;
        __syncthreads();
    }
    if (t < NBLK) bsums[t] = s[t] - v;  // exclusive
}

__global__ __launch_bounds__(1024) void scan_phase3(
    const int* __restrict__ deg, const int* __restrict__ bsums,
    int* __restrict__ row_ptr, int* __restrict__ offs)
{
    __shared__ int s[1024];
    int t = threadIdx.x;
    int i = blockIdx.x * 1024 + t;
    int v = (i < N_NODES) ? deg[i] : 0;
    s[t] = v;
    __syncthreads();
    for (int off = 1; off < 1024; off <<= 1) {
        int u = (t >= off) ? s[t - off] : 0;
        __syncthreads();
        s[t] += u;
        __syncthreads();
    }
    int excl = bsums[blockIdx.x] + s[t] - v;
    if (i < N_NODES) { row_ptr[i] = excl; offs[i] = excl; }
    else if (i == N_NODES) row_ptr[i] = excl;
}

// direct scatter: one 32B-slot record per edge {src, ea(bf16x8)}, 20B burst -> 1 line
__global__ __launch_bounds__(256) void scatter_rec_kernel(
    const int*   __restrict__ src,
    const int*   __restrict__ dst,
    const float* __restrict__ edge_attr,
    int*         __restrict__ offs,
    uint*        __restrict__ rec)   // 8 uints per record
{
    int e = blockIdx.x * 256 + threadIdx.x;
    if (e >= N_EDGES) return;
    int pos = atomicAdd(&offs[dst[e]], 1);
    const float4* ea4 = (const float4*)edge_attr;
    float4 a = ea4[(long)e * 2];
    float4 c = ea4[(long)e * 2 + 1];
    uint* r = rec + (long)pos * 8;
    uint4 w0 = make_uint4((uint)src[e], pack2(a.x, a.y), pack2(a.z, a.w), pack2(c.x, c.y));
    *(uint4*)r = w0;        // 16B
    r[4] = pack2(c.z, c.w); // +4B, same 32B slot -> same line
}

// ---------------- fused GINE layer (bf16 gathers, batch-8) ----------------
__global__ __launch_bounds__(256) void gine_fused2_kernel(
    const ushort* __restrict__ xb_in,
    ushort*       __restrict__ xb_out,
    float*        __restrict__ f32_out,   // nullable: last layer only
    const int*    __restrict__ row_ptr,
    const uint*   __restrict__ rec,
    const float*  __restrict__ W,    // [32][32]
    const float*  __restrict__ b,    // [32]
    const float*  __restrict__ We,   // [8][32]
    const float*  __restrict__ be)   // [32]
{
    __shared__ float W_s[D * D];
    __shared__ float We_s[ED * D];
    __shared__ float b_s[D];
    __shared__ float be_s[D];
    const int t = threadIdx.x;
    for (int i = t; i < D * D; i += 256) W_s[i] = W[i];
    if (t < ED * D) We_s[t] = We[t];
    if (t < D) { b_s[t] = b[t]; be_s[t] = be[t]; }
    __syncthreads();

    const int n = blockIdx.x * 8 + (t >> 5);
    const int d = t & 31;
    if (n >= N_NODES) return;

    // hoist per-lane columns out of LDS
    float wer[ED];
#pragma unroll
    for (int k = 0; k < ED; ++k) wer[k] = We_s[k * D + d];
    const float bed = be_s[d];

    const int row  = row_ptr[n];
    const int rend = row_ptr[n + 1];

    float selfx = bf_us(xb_in[(long)n * D + d]);  // 64B coalesced per group

    float acc = 0.0f;
    for (int pos = row; pos < rend; pos += 8) {
        const int rem = rend - pos;  // >= 1
        // 8 records = 256B coalesced: lane d reads uint2 (8B)
        const uint2* rp = (const uint2*)(rec + (long)pos * 8);
        uint2 v = rp[d];

        int srcs[8];
#pragma unroll
        for (int j = 0; j < 8; ++j) srcs[j] = __shfl((int)v.x, 4 * j, 32);
        const int s0 = srcs[0];  // valid (rem >= 1)

        // phase 1: up to 8 independent 64B gathers
        float xv[8];
#pragma unroll
        for (int j = 0; j < 8; ++j) {
            int sj = (j < rem) ? srcs[j] : s0;
            xv[j] = bf_us(xb_in[(long)sj * D + d]);
        }
        // phase 2: branch-free edge MLP + predicated accumulate
#pragma unroll
        for (int j = 0; j < 8; ++j) {
            uint u01 = (uint)__shfl((int)v.y, 4 * j, 32);
            uint u23 = (uint)__shfl((int)v.x, 4 * j + 1, 32);
            uint u45 = (uint)__shfl((int)v.y, 4 * j + 1, 32);
            uint u67 = (uint)__shfl((int)v.x, 4 * j + 2, 32);
            float e = bed;
            e += bf_lo(u01) * wer[0];
            e += bf_hi(u01) * wer[1];
            e += bf_lo(u23) * wer[2];
            e += bf_hi(u23) * wer[3];
            e += bf_lo(u45) * wer[4];
            e += bf_hi(u45) * wer[5];
            e += bf_lo(u67) * wer[6];
            e += bf_hi(u67) * wer[7];
            float m = fmaxf(xv[j] + e, 0.0f);
            acc += (j < rem) ? m : 0.0f;
        }
    }

    float h = selfx + acc;
    float o = b_s[d];
#pragma unroll
    for (int k = 0; k < D; ++k)
        o += __shfl(h, k, 32) * W_s[k * D + d];
    o = o > 0.0f ? o : NEG_SLOPE * o;
    xb_out[(long)n * D + d] = (ushort)bf16_rne(o);
    if (f32_out) f32_out[(long)n * D + d] = o;
}

// ---------------- round-1 fallback (atomics) ----------------
__global__ __launch_bounds__(256) void gine_edge_kernel(
    const float* __restrict__ x, const float* __restrict__ edge_attr,
    const float* __restrict__ We, const float* __restrict__ be,
    const int* __restrict__ src, const int* __restrict__ dst,
    float* __restrict__ agg)
{
    __shared__ float We_s[ED * D];
    __shared__ float be_s[D];
    int t = threadIdx.x;
    if (t < ED * D) We_s[t] = We[t];
    if (t < D) be_s[t] = be[t];
    __syncthreads();
    long gtid = (long)blockIdx.x * blockDim.x + t;
    int e = (int)(gtid >> 5), d = (int)(gtid & 31);
    if (e >= N_EDGES) return;
    int s = src[e], dn = dst[e];
    float acc = be_s[d];
#pragma unroll
    for (int k = 0; k < ED; ++k)
        acc += edge_attr[(long)e * ED + k] * We_s[k * D + d];
    float m = fmaxf(x[(long)s * D + d] + acc, 0.0f);
    atomicAdd(&agg[(long)dn * D + d], m);
}

__global__ __launch_bounds__(256) void gine_node_kernel(
    float* __restrict__ x, const float* __restrict__ agg,
    const float* __restrict__ W, const float* __restrict__ b)
{
    __shared__ float W_s[D * D];
    __shared__ float b_s[D];
    int t = threadIdx.x;
    for (int i = t; i < D * D; i += 256) W_s[i] = W[i];
    if (t < D) b_s[t] = b[t];
    __syncthreads();
    long gtid = (long)blockIdx.x * blockDim.x + t;
    int n = (int)(gtid >> 5), d = (int)(gtid & 31);
    if (n >= N_NODES) return;
    float h = x[(long)n * D + d] + agg[(long)n * D + d];
    float acc = b_s[d];
#pragma unroll
    for (int k = 0; k < D; ++k)
        acc += __shfl(h, k, D) * W_s[k * D + d];
    x[(long)n * D + d] = acc > 0.0f ? acc : NEG_SLOPE * acc;
}

// ---------------- launch ----------------

extern "C" void kernel_launch(void* const* d_in, const int* in_sizes, int n_in,
                              void* d_out, int out_size, void* d_ws, size_t ws_size,
                              hipStream_t stream) {
    const float* x_in      = (const float*)d_in[0];
    const float* edge_attr = (const float*)d_in[1];
    const float* W         = (const float*)d_in[2];
    const float* b         = (const float*)d_in[3];
    const float* We        = (const float*)d_in[4];
    const float* be        = (const float*)d_in[5];
    const int*   ei        = (const int*)d_in[6];
    const int* src = ei;
    const int* dst = ei + N_EDGES;

    const size_t xbytes  = (size_t)N_NODES * D * sizeof(float);
    const size_t xbbytes = (size_t)N_NODES * D * sizeof(ushort);  // 6.4 MB

    auto align = [](size_t v) { return (v + 255) & ~(size_t)255; };
    size_t off_xba  = 0;
    size_t off_xbb  = align(off_xba + xbbytes);
    size_t off_rp   = align(off_xbb + xbbytes);                     // row_ptr (N+1)
    size_t off_offs = align(off_rp + (N_NODES + 1) * sizeof(int));  // offs (N)
    size_t off_deg  = align(off_offs + N_NODES * sizeof(int));      // deg (N)
    size_t off_bs   = align(off_deg + N_NODES * sizeof(int));       // bsums (128)
    size_t off_rec  = align(off_bs + 128 * sizeof(int));            // rec (E * 32B)
    size_t need     = off_rec + (size_t)N_EDGES * 8 * sizeof(uint) + 256;  // +tail pad

    if (ws_size >= need) {
        char* ws = (char*)d_ws;
        ushort* xbA    = (ushort*)(ws + off_xba);
        ushort* xbB    = (ushort*)(ws + off_xbb);
        int*   row_ptr = (int*)   (ws + off_rp);
        int*   offs    = (int*)   (ws + off_offs);
        int*   deg     = (int*)   (ws + off_deg);
        int*   bsums   = (int*)   (ws + off_bs);
        uint*  rec     = (uint*)  (ws + off_rec);

        pack_x_kernel<<<(N_NODES * D / 4 + 255) / 256, 256, 0, stream>>>(x_in, xbA);

        hipMemsetAsync(deg, 0, N_NODES * sizeof(int), stream);
        hist_kernel<<<(N_EDGES / 4 + 255) / 256, 256, 0, stream>>>(dst, deg);
        scan_phase1<<<NBLK, 1024, 0, stream>>>(deg, bsums);
        scan_phase2<<<1, 128, 0, stream>>>(bsums);
        scan_phase3<<<NBLK, 1024, 0, stream>>>(deg, bsums, row_ptr, offs);
        scatter_rec_kernel<<<(N_EDGES + 255) / 256, 256, 0, stream>>>(
            src, dst, edge_attr, offs, rec);

        float* xout = (float*)d_out;
        dim3 blk(256), grid((N_NODES + 7) / 8);
        gine_fused2_kernel<<<grid, blk, 0, stream>>>(xbA, xbB, nullptr, row_ptr, rec,
            W, b, We, be);
        gine_fused2_kernel<<<grid, blk, 0, stream>>>(xbB, xbA, nullptr, row_ptr, rec,
            W + D * D, b + D, We + ED * D, be + D);
        gine_fused2_kernel<<<grid, blk, 0, stream>>>(xbA, xbB, xout, row_ptr, rec,
            W + 2 * D * D, b + 2 * D, We + 2 * ED * D, be + 2 * D);
    } else {
        float* x = (float*)d_out;
        float* agg = (float*)d_ws;
        hipMemcpyAsync(x, x_in, xbytes, hipMemcpyDeviceToDevice, stream);
        dim3 eblk(256), egrid(((long)N_EDGES * D + 255) / 256);
        dim3 nblk(256), ngrid(((long)N_NODES * D + 255) / 256);
        for (int l = 0; l < 3; ++l) {
            hipMemsetAsync(agg, 0, xbytes, stream);
            gine_edge_kernel<<<egrid, eblk, 0, stream>>>(
                x, edge_attr, We + (size_t)l * ED * D, be + (size_t)l * D, src, dst, agg);
            gine_node_kernel<<<ngrid, nblk, 0, stream>>>(
                x, agg, W + (size_t)l * D * D, b + (size_t)l * D);
        }
    }
}